// Round 9
// baseline (234.022 us; speedup 1.0000x reference)
//
#include <hip/hip_runtime.h>

typedef unsigned short u16;
typedef __bf16 bf16x8 __attribute__((ext_vector_type(8)));
typedef float  f32x4  __attribute__((ext_vector_type(4)));

#define NEDGES 65536
#define NNODES 8192
#define EPB 64

#define PW0f       0.14433756729740643f   // (1/48)^0.5
#define PW1f       0.21650635094610965f   // (3/64)^0.5
#define INV_SQRT3f 0.5773502691896258f
#define INV_SQRT6f 0.4082482904638631f
#define SILU_NORMf 1.6790425f

// workspace layout (bytes)
#define WT2_OFF 0          // u16[2560][64]  Wfc2^T, 0.125*region scale folded
#define WT0_OFF 163840     // u16 elem offset: [64][64] Wfc0^T * 0.125
#define WT1_OFF 167936     // u16 elem offset: [64][64] Wfc1^T * 0.125
#define WS_ELEMS 172032    // u16 elements of weight tables

#define OFF_CNT   344064   // int[8192]   per-node edge count
#define OFF_OFS   376832   // int[8193]   CSR offsets
#define OFF_CUR   409856   // int[8192]   fill cursors
#define OFF_ELIST 442624   // int[65536]  edge ids grouped by dst
#define OFF_MSG   704768   // float[65536][80] per-edge messages
#define WS_NEED   21676288

#define HSTR 72            // padded bf16 row stride for h0/h1 LDS tiles

__device__ __forceinline__ float silu_n(float z) {
    return SILU_NORMf * z / (1.0f + __expf(-z));
}
__device__ __forceinline__ u16 f2bf(float f) {
    return __builtin_bit_cast(u16, (__bf16)f);
}
__device__ __forceinline__ float bf2f(u16 u) {
    unsigned v = ((unsigned)u) << 16;
    return __builtin_bit_cast(float, v);
}
__device__ __forceinline__ bf16x8 ld_bf8(const u16* p) {
    return *reinterpret_cast<const bf16x8*>(p);
}
__device__ __forceinline__ bf16x8 cvt_bf8(const float* p) {
    float4 a = *reinterpret_cast<const float4*>(p);
    float4 b = *reinterpret_cast<const float4*>(p + 4);
    bf16x8 r;
    r[0]=(__bf16)a.x; r[1]=(__bf16)a.y; r[2]=(__bf16)a.z; r[3]=(__bf16)a.w;
    r[4]=(__bf16)b.x; r[5]=(__bf16)b.y; r[6]=(__bf16)b.z; r[7]=(__bf16)b.w;
    return r;
}
#define MFMA16(A,B,C) __builtin_amdgcn_mfma_f32_16x16x32_bf16(A,B,C,0,0,0)

// ---------------------------------------------------------------------------
// k_zero: clear the per-node histogram counters.
// ---------------------------------------------------------------------------
__global__ void k_zero(int* __restrict__ cnt) {
    int i = blockIdx.x * 256 + threadIdx.x;
    if (i < NNODES) cnt[i] = 0;
}

// ---------------------------------------------------------------------------
// Prep kernel (fused): blocks [0,672) transpose+scale+bf16 the MLP weights
// into d_ws; blocks [672,3232) compute the self-connection into d_out
// (re-initializes d_out every call); blocks [3232,3488) histogram dst.
// ---------------------------------------------------------------------------
__global__ void k_prep(const float* __restrict__ Wfc0,
                       const float* __restrict__ Wfc1,
                       const float* __restrict__ Wfc2,
                       const float* __restrict__ node_feat,
                       const float* __restrict__ Wsc0,
                       const float* __restrict__ Wsc1,
                       const int*   __restrict__ eidx,
                       u16* __restrict__ ws,
                       int* __restrict__ cnt,
                       float* __restrict__ out)
{
    const int bid = blockIdx.x;
    if (bid < 672) {
        int gid = bid * 256 + threadIdx.x;
        if (gid < 163840) {                 // gid = k*2560 + j (read-coalesced)
            int k = gid / 2560;
            int j = gid - k * 2560;
            float s;
            if (j < 1024)      s = PW0f;
            else if (j < 1536) s = PW0f * INV_SQRT3f;
            else if (j < 2304) s = PW1f * INV_SQRT3f;
            else               s = PW1f * INV_SQRT6f;
            ws[WT2_OFF + j * 64 + k] = f2bf(Wfc2[gid] * (0.125f * s));
        } else if (gid < WT1_OFF) {
            int i = gid - WT0_OFF;
            int k = i >> 6, n = i & 63;
            ws[WT0_OFF + n * 64 + k] = f2bf(Wfc0[i] * 0.125f);
        } else if (gid < WS_ELEMS) {
            int i = gid - WT1_OFF;
            int k = i >> 6, n = i & 63;
            ws[WT1_OFF + n * 64 + k] = f2bf(Wfc1[i] * 0.125f);
        }
    } else if (bid < 3232) {
        int gid = (bid - 672) * 256 + threadIdx.x;
        if (gid >= NNODES * 80) return;
        int n = gid / 80;
        int s = gid - n * 80;
        const float* nf = node_feat + (size_t)n * 80;
        float r;
        if (s < 32) {
            float a = 0.f;
            #pragma unroll
            for (int u = 0; u < 32; ++u) a += nf[u] * Wsc0[u * 32 + s];
            r = a * 0.17677669529663687f;   // 1/sqrt(32)
        } else {
            int v = (s - 32) / 3;
            int k = (s - 32) - v * 3;
            float a = 0.f;
            #pragma unroll
            for (int u = 0; u < 16; ++u) a += nf[32 + u * 3 + k] * Wsc1[u * 16 + v];
            r = a * 0.25f;                   // 1/sqrt(16)
        }
        out[gid] = r;
    } else {
        int e = (bid - 3232) * 256 + threadIdx.x;
        if (e < NEDGES) atomicAdd(&cnt[eidx[NEDGES + e]], 1);
    }
}

// ---------------------------------------------------------------------------
// k_scan: exclusive prefix sum over cnt[8192] -> ofs[8193], cur = ofs copy.
// ---------------------------------------------------------------------------
__global__ __launch_bounds__(1024) void k_scan(const int* __restrict__ cnt,
                                               int* __restrict__ ofs,
                                               int* __restrict__ cur)
{
    __shared__ int ps[1024];
    const int t = threadIdx.x;
    const int base = t * 8;
    int v[8]; int s = 0;
    #pragma unroll
    for (int i = 0; i < 8; ++i) { v[i] = cnt[base + i]; s += v[i]; }
    ps[t] = s;
    __syncthreads();
    int acc = s;
    for (int off = 1; off < 1024; off <<= 1) {
        int x = (t >= off) ? ps[t - off] : 0;
        __syncthreads();
        acc += x;
        ps[t] = acc;
        __syncthreads();
    }
    int run = acc - s;                       // exclusive base for this thread
    #pragma unroll
    for (int i = 0; i < 8; ++i) { ofs[base + i] = run; cur[base + i] = run; run += v[i]; }
    if (t == 1023) ofs[NNODES] = run;
}

// ---------------------------------------------------------------------------
// k_fill: bucket edge ids by dst via cursor atomics.
// ---------------------------------------------------------------------------
__global__ void k_fill(const int* __restrict__ eidx,
                       int* __restrict__ cur,
                       int* __restrict__ elist)
{
    int e = blockIdx.x * 256 + threadIdx.x;
    int d = eidx[NEDGES + e];
    int pos = atomicAdd(&cur[d], 1);
    elist[pos] = e;
}

// ---------------------------------------------------------------------------
// Main fused kernel (round-7 body, verified 70us): 64 edges/block, 4 waves,
// now 4 blocks/CU (launch_bounds 4) and a 4-tile-deep A-register pipeline
// (P/Q ping-pong; each pair reloaded right after its MFMA consumes it ->
// prefetch distance ~4 tiles ~ 320 cyc > L2 latency).
// Wave roles (rotated per block):
//   role0: tiles [0,48)    W1    -> msg0   role1: [48,96)  W1+W2 -> msg0
//   role2: tiles [96,128)  W3    -> msg1   role3: [128,160) W4+W5 -> msg1
// TAIL=1: coalesced store of the 64x80 message tile to msgbuf (no atomics).
// ---------------------------------------------------------------------------
template<int TAIL>
__global__ __launch_bounds__(256, 4) void k_main(
    const int*   __restrict__ eidx,
    const float* __restrict__ node_feat,
    const float* __restrict__ edge_feat,
    const float* __restrict__ edge_embed,
    const u16*   __restrict__ ws,
    float*       __restrict__ msgbuf,
    float*       __restrict__ out)
{
    __shared__ __align__(16) char smem[40192];
    u16*   h1S   = (u16*)(smem);            // [64][72]  9216 B
    u16*   c12S  = (u16*)(smem + 9216);     // [48][64]  6144 B
    u16*   coefB = (u16*)(smem + 15360);    // [192][64] 24576 B
    int*   dstS  = (int*)(smem + 39936);    // 256 B
    u16*   h0S   = (u16*)(smem + 15360);    // alias: [64][72] during fc phase
    float* msgS  = (float*)(smem + 9216);   // alias: [64][81] f32 at reduce

    const int t    = threadIdx.x;
    const int lane = t & 63;
    const int l15  = lane & 15;
    const int lq   = lane >> 4;
    const int wid  = t >> 6;
    const int role = (wid + blockIdx.x) & 3;
    const int eg0  = blockIdx.x * EPB;

    const u16* WT2 = ws + WT2_OFF;
    const u16* WT0 = ws + WT0_OFF;
    const u16* WT1 = ws + WT1_OFF;

    // ---------------- fc0: h0 = silu(emb @ W0/8), 16 edges per wave --------
    {
        const float* erow = edge_embed + (size_t)(eg0 + wid * 16 + l15) * 64 + 8 * lq;
        bf16x8 eB0 = cvt_bf8(erow);
        bf16x8 eB1 = cvt_bf8(erow + 32);
        #pragma unroll
        for (int ntl = 0; ntl < 4; ++ntl) {
            const u16* a = WT0 + (ntl * 16 + l15) * 64 + 8 * lq;
            bf16x8 A0 = ld_bf8(a);
            bf16x8 A1 = ld_bf8(a + 32);
            f32x4 z = {0.f, 0.f, 0.f, 0.f};
            z = MFMA16(A0, eB0, z);
            f32x4 dd = MFMA16(A1, eB1, z);
            ushort4 pk;
            pk.x = f2bf(silu_n(dd[0]));
            pk.y = f2bf(silu_n(dd[1]));
            pk.z = f2bf(silu_n(dd[2]));
            pk.w = f2bf(silu_n(dd[3]));
            *(ushort4*)&h0S[(wid * 16 + l15) * HSTR + ntl * 16 + lq * 4] = pk;
        }
    }
    // ---------------- fc1: h1 = silu(h0 @ W1/8) (own wave's rows) ----------
    {
        const u16* hrow = h0S + (wid * 16 + l15) * HSTR + 8 * lq;
        bf16x8 hB0 = ld_bf8(hrow);
        bf16x8 hB1 = ld_bf8(hrow + 32);
        #pragma unroll
        for (int ntl = 0; ntl < 4; ++ntl) {
            const u16* a = WT1 + (ntl * 16 + l15) * 64 + 8 * lq;
            bf16x8 A0 = ld_bf8(a);
            bf16x8 A1 = ld_bf8(a + 32);
            f32x4 z = {0.f, 0.f, 0.f, 0.f};
            z = MFMA16(A0, hB0, z);
            f32x4 dd = MFMA16(A1, hB1, z);
            ushort4 pk;
            pk.x = f2bf(silu_n(dd[0]));
            pk.y = f2bf(silu_n(dd[1]));
            pk.z = f2bf(silu_n(dd[2]));
            pk.w = f2bf(silu_n(dd[3]));
            *(ushort4*)&h1S[(wid * 16 + l15) * HSTR + ntl * 16 + lq * 4] = pk;
        }
    }
    __syncthreads();   // h0S dead; coefB alias region reused below

    // ---------------- left-factor coef tables, 4 threads per edge ----------
    {
        const int e   = t & 63;
        const int q   = t >> 6;
        const int eg  = eg0 + e;
        const int src = eidx[eg];
        const float* nf = node_feat + (size_t)src * 80;
        const float* ef = edge_feat + (size_t)eg * 4;
        if (q == 0) {
            dstS[e] = eidx[NEDGES + eg];
            const float y0 = ef[0];
            #pragma unroll
            for (int u = 0; u < 32; ++u) c12S[u * 64 + e] = f2bf(nf[u] * y0);
        } else if (q == 1) {
            const float ya = ef[1], yb = ef[2], yc = ef[3];
            #pragma unroll
            for (int u = 0; u < 16; ++u) {
                float d = nf[32 + u * 3] * ya + nf[32 + u * 3 + 1] * yb
                        + nf[32 + u * 3 + 2] * yc;
                c12S[(32 + u) * 64 + e] = f2bf(d);
            }
        } else if (q == 2) {
            const float ya = ef[1], yb = ef[2], yc = ef[3];
            #pragma unroll
            for (int u = 0; u < 32; ++u) {
                const float x = nf[u];
                coefB[(u * 3 + 0) * 64 + e] = f2bf(x * ya);
                coefB[(u * 3 + 1) * 64 + e] = f2bf(x * yb);
                coefB[(u * 3 + 2) * 64 + e] = f2bf(x * yc);
            }
        } else {
            const float y0 = ef[0], ya = ef[1], yb = ef[2], yc = ef[3];
            #pragma unroll
            for (int u = 0; u < 16; ++u) {
                const float xa = nf[32 + u * 3], xb = nf[32 + u * 3 + 1], xc = nf[32 + u * 3 + 2];
                coefB[(96 + u * 3 + 0) * 64 + e] = f2bf(xa * y0);
                coefB[(96 + u * 3 + 1) * 64 + e] = f2bf(xb * y0);
                coefB[(96 + u * 3 + 2) * 64 + e] = f2bf(xc * y0);
                coefB[(144 + u * 3 + 0) * 64 + e] = f2bf(xb * yc - xc * yb);
                coefB[(144 + u * 3 + 1) * 64 + e] = f2bf(xc * ya - xa * yc);
                coefB[(144 + u * 3 + 2) * 64 + e] = f2bf(xa * yb - xb * ya);
            }
        }
    }
    __syncthreads();

    // ---------------- B fragments (all 64 edges) ---------------------------
    bf16x8 hb[4][2];
    #pragma unroll
    for (int eg = 0; eg < 4; ++eg) {
        const u16* r = h1S + (eg * 16 + l15) * HSTR + 8 * lq;
        hb[eg][0] = ld_bf8(r);
        hb[eg][1] = ld_bf8(r + 32);
    }

    float acc[48];
    #pragma unroll
    for (int i = 0; i < 48; ++i) acc[i] = 0.f;

    int t0, ntile;
    if (role < 2) { t0 = role * 48;            ntile = 48; }
    else          { t0 = 96 + (role - 2) * 32; ntile = 32; }

    const u16* Aw = WT2 + l15 * 64 + 8 * lq;   // + 1024 elems per tile

#define COMPUTE(A0_, A1_, D_)                                          \
    {                                                                  \
        _Pragma("unroll")                                              \
        for (int eg = 0; eg < 4; ++eg) {                               \
            f32x4 z = {0.f, 0.f, 0.f, 0.f};                            \
            z = MFMA16(A0_, hb[eg][0], z);                             \
            D_[eg] = MFMA16(A1_, hb[eg][1], z);                        \
        }                                                              \
    }

#define EPILOGUE(D_, TT_, HS_)                                              \
    {                                                                       \
        if (role < 2) {                                                     \
            const u16* cr = c12S + ((TT_) >> 1) * 64;                       \
            _Pragma("unroll")                                               \
            for (int eg = 0; eg < 4; ++eg) {                                \
                const float c = bf2f(cr[eg * 16 + l15]);                    \
                _Pragma("unroll")                                           \
                for (int r = 0; r < 4; ++r)                                 \
                    acc[eg * 8 + (HS_) * 4 + r] += c * D_[eg][r];           \
            }                                                               \
        } else {                                                            \
            const u16* cr = coefB + ((TT_) - 96) * 192;                     \
            _Pragma("unroll")                                               \
            for (int eg = 0; eg < 4; ++eg) {                                \
                const int e16 = eg * 16 + l15;                              \
                const float c0 = bf2f(cr[e16]);                             \
                const float c1 = bf2f(cr[64 + e16]);                        \
                const float c2 = bf2f(cr[128 + e16]);                       \
                _Pragma("unroll")                                           \
                for (int r = 0; r < 4; ++r) {                               \
                    const float dv = D_[eg][r];                             \
                    acc[eg * 12 + r * 3 + 0] += c0 * dv;                    \
                    acc[eg * 12 + r * 3 + 1] += c1 * dv;                    \
                    acc[eg * 12 + r * 3 + 2] += c2 * dv;                    \
                }                                                           \
            }                                                               \
        }                                                                   \
    }

    // ---------------- main fc2 loop: 4-tile P/Q ping-pong pipeline ---------
    bf16x8 Pa0, Pa1, Pb0, Pb1, Qa0, Qa1, Qb0, Qb1;
    {
        const u16* p0 = Aw + (size_t)(t0 + 0) * 1024;
        Pa0 = ld_bf8(p0); Pa1 = ld_bf8(p0 + 32);
        const u16* p1 = Aw + (size_t)(t0 + 1) * 1024;
        Pb0 = ld_bf8(p1); Pb1 = ld_bf8(p1 + 32);
        const u16* p2 = Aw + (size_t)(t0 + 2) * 1024;
        Qa0 = ld_bf8(p2); Qa1 = ld_bf8(p2 + 32);
        const u16* p3 = Aw + (size_t)(t0 + 3) * 1024;
        Qb0 = ld_bf8(p3); Qb1 = ld_bf8(p3 + 32);
    }
    const int nq = ntile >> 2;
    #pragma unroll 1
    for (int p = 0; p < nq; ++p) {
        const int tt = t0 + 4 * p;
        const bool more = (p + 1 < nq);
        f32x4 d[4];
        COMPUTE(Pa0, Pa1, d);
        EPILOGUE(d, tt, 0);
        if (more) { const u16* q_ = Aw + (size_t)(tt + 4) * 1024;
                    Pa0 = ld_bf8(q_); Pa1 = ld_bf8(q_ + 32); }
        COMPUTE(Pb0, Pb1, d);
        EPILOGUE(d, tt + 1, 1);
        if (more) { const u16* q_ = Aw + (size_t)(tt + 5) * 1024;
                    Pb0 = ld_bf8(q_); Pb1 = ld_bf8(q_ + 32); }
        COMPUTE(Qa0, Qa1, d);
        EPILOGUE(d, tt + 2, 0);
        if (more) { const u16* q_ = Aw + (size_t)(tt + 6) * 1024;
                    Qa0 = ld_bf8(q_); Qa1 = ld_bf8(q_ + 32); }
        COMPUTE(Qb0, Qb1, d);
        EPILOGUE(d, tt + 3, 1);
        if (more) { const u16* q_ = Aw + (size_t)(tt + 7) * 1024;
                    Qb0 = ld_bf8(q_); Qb1 = ld_bf8(q_ + 32); }
    }
#undef COMPUTE
#undef EPILOGUE

    // ---------------- cross-wave reduce (owner-ordered, no atomics) --------
    __syncthreads();   // all waves done reading c12S/coefB; msgS aliases them
    if (role == 0) {
        #pragma unroll
        for (int eg = 0; eg < 4; ++eg) {
            float* mb = msgS + (eg * 16 + l15) * 81;
            #pragma unroll
            for (int hs = 0; hs < 2; ++hs)
                #pragma unroll
                for (int r = 0; r < 4; ++r)
                    mb[hs * 16 + lq * 4 + r] = acc[eg * 8 + hs * 4 + r];
        }
    } else if (role == 2) {
        #pragma unroll
        for (int eg = 0; eg < 4; ++eg) {
            float* mb = msgS + (eg * 16 + l15) * 81 + 32;
            #pragma unroll
            for (int r = 0; r < 4; ++r)
                #pragma unroll
                for (int k = 0; k < 3; ++k)
                    mb[(lq * 4 + r) * 3 + k] = acc[eg * 12 + r * 3 + k];
        }
    }
    __syncthreads();
    if (role == 1) {
        #pragma unroll
        for (int eg = 0; eg < 4; ++eg) {
            float* mb = msgS + (eg * 16 + l15) * 81;
            #pragma unroll
            for (int hs = 0; hs < 2; ++hs)
                #pragma unroll
                for (int r = 0; r < 4; ++r)
                    mb[hs * 16 + lq * 4 + r] += acc[eg * 8 + hs * 4 + r];
        }
    } else if (role == 3) {
        #pragma unroll
        for (int eg = 0; eg < 4; ++eg) {
            float* mb = msgS + (eg * 16 + l15) * 81 + 32;
            #pragma unroll
            for (int r = 0; r < 4; ++r)
                #pragma unroll
                for (int k = 0; k < 3; ++k)
                    mb[(lq * 4 + r) * 3 + k] += acc[eg * 12 + r * 3 + k];
        }
    }
    __syncthreads();

    // ---------------- tail --------------------------------------------------
    if (TAIL == 1) {
        // coalesced store of the 64x80 tile to msgbuf (no atomics)
        float* mrow = msgbuf + (size_t)eg0 * 80;
        for (int idx = t; idx < EPB * 80; idx += 256) {
            const int e = idx / 80;
            const int s = idx - e * 80;
            mrow[idx] = msgS[e * 81 + s];
        }
    } else {
        // legacy atomic scatter (fallback when workspace is too small)
        for (int idx = t; idx < 64 * 81; idx += 256) {
            const int e = idx / 81;
            const int s = idx - e * 81;
            if (s < 80)
                atomicAdd(out + (size_t)dstS[e] * 80 + s, msgS[idx]);
        }
    }
}

// ---------------------------------------------------------------------------
// k_gather: one wave per node; sum its incident edges' msg rows, add to out.
// ---------------------------------------------------------------------------
__global__ __launch_bounds__(256) void k_gather(const int* __restrict__ ofs,
                                                const int* __restrict__ elist,
                                                const float* __restrict__ msg,
                                                float* __restrict__ out)
{
    const int lane = threadIdx.x & 63;
    const int n = blockIdx.x * 4 + (threadIdx.x >> 6);
    const int jb = ofs[n], je = ofs[n + 1];
    float v0 = 0.f, v1 = 0.f;
    int j = jb;
    for (; j + 2 <= je; j += 2) {
        const int e0 = elist[j], e1 = elist[j + 1];
        const float* m0 = msg + (size_t)e0 * 80;
        const float* m1 = msg + (size_t)e1 * 80;
        v0 += m0[lane] + m1[lane];
        if (lane < 16) v1 += m0[64 + lane] + m1[64 + lane];
    }
    if (j < je) {
        const float* m0 = msg + (size_t)elist[j] * 80;
        v0 += m0[lane];
        if (lane < 16) v1 += m0[64 + lane];
    }
    float* op = out + (size_t)n * 80;
    op[lane] += v0;
    if (lane < 16) op[64 + lane] += v1;
}

extern "C" void kernel_launch(void* const* d_in, const int* in_sizes, int n_in,
                              void* d_out, int out_size, void* d_ws, size_t ws_size,
                              hipStream_t stream) {
    const int*   eidx       = (const int*)d_in[0];
    const float* node_feat  = (const float*)d_in[1];
    const float* edge_feat  = (const float*)d_in[2];
    const float* edge_embed = (const float*)d_in[3];
    const float* Wfc0       = (const float*)d_in[5];
    const float* Wfc1       = (const float*)d_in[6];
    const float* Wfc2       = (const float*)d_in[7];
    const float* Wsc0       = (const float*)d_in[8];
    const float* Wsc1       = (const float*)d_in[9];
    float* out = (float*)d_out;
    char*  wsb = (char*)d_ws;
    u16*   ws  = (u16*)d_ws;

    if (ws_size < (size_t)WS_ELEMS * sizeof(u16)) return;  // need >= 344 KB

    const bool big = ws_size >= (size_t)WS_NEED;
    int*   cnt    = (int*)(wsb + OFF_CNT);
    int*   ofs    = (int*)(wsb + OFF_OFS);
    int*   cur    = (int*)(wsb + OFF_CUR);
    int*   elist  = (int*)(wsb + OFF_ELIST);
    float* msgbuf = (float*)(wsb + OFF_MSG);

    if (big) {
        hipLaunchKernelGGL(k_zero, dim3(32), dim3(256), 0, stream, cnt);
        hipLaunchKernelGGL(k_prep, dim3(3488), dim3(256), 0, stream,
                           Wfc0, Wfc1, Wfc2, node_feat, Wsc0, Wsc1, eidx, ws, cnt, out);
        hipLaunchKernelGGL(k_scan, dim3(1), dim3(1024), 0, stream, cnt, ofs, cur);
        hipLaunchKernelGGL(k_fill, dim3(NEDGES / 256), dim3(256), 0, stream,
                           eidx, cur, elist);
        hipLaunchKernelGGL((k_main<1>), dim3(NEDGES / EPB), dim3(256), 0, stream,
                           eidx, node_feat, edge_feat, edge_embed, ws, msgbuf, out);
        hipLaunchKernelGGL(k_gather, dim3(NNODES / 4), dim3(256), 0, stream,
                           ofs, elist, msgbuf, out);
    } else {
        hipLaunchKernelGGL(k_prep, dim3(3232), dim3(256), 0, stream,
                           Wfc0, Wfc1, Wfc2, node_feat, Wsc0, Wsc1, eidx, ws, cnt, out);
        hipLaunchKernelGGL((k_main<0>), dim3(NEDGES / EPB), dim3(256), 0, stream,
                           eidx, node_feat, edge_feat, edge_embed, ws, msgbuf, out);
    }
}

// Round 10
// 101.896 us; speedup vs baseline: 2.2967x; 2.2967x over previous
//
#include <hip/hip_runtime.h>

typedef unsigned short u16;
typedef __bf16 bf16x8 __attribute__((ext_vector_type(8)));
typedef float  f32x4  __attribute__((ext_vector_type(4)));

#define NEDGES 65536
#define NNODES 8192
#define EPB 64

#define PW0f       0.14433756729740643f   // (1/48)^0.5
#define PW1f       0.21650635094610965f   // (3/64)^0.5
#define INV_SQRT3f 0.5773502691896258f
#define INV_SQRT6f 0.4082482904638631f
#define SILU_NORMf 1.6790425f

// workspace layout (bytes)
#define WT2_OFF 0          // u16[2560][64]  Wfc2^T, 0.125*region scale folded
#define WT0_OFF 163840     // u16 elem offset: [64][64] Wfc0^T * 0.125
#define WT1_OFF 167936     // u16 elem offset: [64][64] Wfc1^T * 0.125
#define WS_ELEMS 172032    // u16 elements of weight tables

#define OFF_CNT   344064   // int[8192]   per-node edge count
#define OFF_OFS   376832   // int[8193]   CSR offsets
#define OFF_CUR   409856   // int[8192]   fill cursors
#define OFF_ELIST 442624   // int[65536]  edge ids grouped by dst
#define OFF_MSG   704768   // float[65536][80] per-edge messages
#define WS_NEED   21676288

#define HSTR 72            // padded bf16 row stride for h0/h1 LDS tiles

__device__ __forceinline__ float silu_n(float z) {
    return SILU_NORMf * z / (1.0f + __expf(-z));
}
__device__ __forceinline__ u16 f2bf(float f) {
    return __builtin_bit_cast(u16, (__bf16)f);
}
__device__ __forceinline__ float bf2f(u16 u) {
    unsigned v = ((unsigned)u) << 16;
    return __builtin_bit_cast(float, v);
}
__device__ __forceinline__ bf16x8 ld_bf8(const u16* p) {
    return *reinterpret_cast<const bf16x8*>(p);
}
__device__ __forceinline__ bf16x8 cvt_bf8(const float* p) {
    float4 a = *reinterpret_cast<const float4*>(p);
    float4 b = *reinterpret_cast<const float4*>(p + 4);
    bf16x8 r;
    r[0]=(__bf16)a.x; r[1]=(__bf16)a.y; r[2]=(__bf16)a.z; r[3]=(__bf16)a.w;
    r[4]=(__bf16)b.x; r[5]=(__bf16)b.y; r[6]=(__bf16)b.z; r[7]=(__bf16)b.w;
    return r;
}
#define MFMA16(A,B,C) __builtin_amdgcn_mfma_f32_16x16x32_bf16(A,B,C,0,0,0)

// ---------------------------------------------------------------------------
// k_zero: clear the per-node histogram counters.
// ---------------------------------------------------------------------------
__global__ void k_zero(int* __restrict__ cnt) {
    int i = blockIdx.x * 256 + threadIdx.x;
    if (i < NNODES) cnt[i] = 0;
}

// ---------------------------------------------------------------------------
// Prep kernel (fused): blocks [0,672) transpose+scale+bf16 the MLP weights
// into d_ws; blocks [672,3232) compute the self-connection into d_out
// (re-initializes d_out every call); blocks [3232,3488) histogram dst.
// ---------------------------------------------------------------------------
__global__ void k_prep(const float* __restrict__ Wfc0,
                       const float* __restrict__ Wfc1,
                       const float* __restrict__ Wfc2,
                       const float* __restrict__ node_feat,
                       const float* __restrict__ Wsc0,
                       const float* __restrict__ Wsc1,
                       const int*   __restrict__ eidx,
                       u16* __restrict__ ws,
                       int* __restrict__ cnt,
                       float* __restrict__ out)
{
    const int bid = blockIdx.x;
    if (bid < 672) {
        int gid = bid * 256 + threadIdx.x;
        if (gid < 163840) {                 // gid = k*2560 + j (read-coalesced)
            int k = gid / 2560;
            int j = gid - k * 2560;
            float s;
            if (j < 1024)      s = PW0f;
            else if (j < 1536) s = PW0f * INV_SQRT3f;
            else if (j < 2304) s = PW1f * INV_SQRT3f;
            else               s = PW1f * INV_SQRT6f;
            ws[WT2_OFF + j * 64 + k] = f2bf(Wfc2[gid] * (0.125f * s));
        } else if (gid < WT1_OFF) {
            int i = gid - WT0_OFF;
            int k = i >> 6, n = i & 63;
            ws[WT0_OFF + n * 64 + k] = f2bf(Wfc0[i] * 0.125f);
        } else if (gid < WS_ELEMS) {
            int i = gid - WT1_OFF;
            int k = i >> 6, n = i & 63;
            ws[WT1_OFF + n * 64 + k] = f2bf(Wfc1[i] * 0.125f);
        }
    } else if (bid < 3232) {
        int gid = (bid - 672) * 256 + threadIdx.x;
        if (gid >= NNODES * 80) return;
        int n = gid / 80;
        int s = gid - n * 80;
        const float* nf = node_feat + (size_t)n * 80;
        float r;
        if (s < 32) {
            float a = 0.f;
            #pragma unroll
            for (int u = 0; u < 32; ++u) a += nf[u] * Wsc0[u * 32 + s];
            r = a * 0.17677669529663687f;   // 1/sqrt(32)
        } else {
            int v = (s - 32) / 3;
            int k = (s - 32) - v * 3;
            float a = 0.f;
            #pragma unroll
            for (int u = 0; u < 16; ++u) a += nf[32 + u * 3 + k] * Wsc1[u * 16 + v];
            r = a * 0.25f;                   // 1/sqrt(16)
        }
        out[gid] = r;
    } else {
        int e = (bid - 3232) * 256 + threadIdx.x;
        if (e < NEDGES) atomicAdd(&cnt[eidx[NEDGES + e]], 1);
    }
}

// ---------------------------------------------------------------------------
// k_scan: exclusive prefix sum over cnt[8192] -> ofs[8193], cur = ofs copy.
// ---------------------------------------------------------------------------
__global__ __launch_bounds__(1024) void k_scan(const int* __restrict__ cnt,
                                               int* __restrict__ ofs,
                                               int* __restrict__ cur)
{
    __shared__ int ps[1024];
    const int t = threadIdx.x;
    const int base = t * 8;
    int v[8]; int s = 0;
    #pragma unroll
    for (int i = 0; i < 8; ++i) { v[i] = cnt[base + i]; s += v[i]; }
    ps[t] = s;
    __syncthreads();
    int acc = s;
    for (int off = 1; off < 1024; off <<= 1) {
        int x = (t >= off) ? ps[t - off] : 0;
        __syncthreads();
        acc += x;
        ps[t] = acc;
        __syncthreads();
    }
    int run = acc - s;                       // exclusive base for this thread
    #pragma unroll
    for (int i = 0; i < 8; ++i) { ofs[base + i] = run; cur[base + i] = run; run += v[i]; }
    if (t == 1023) ofs[NNODES] = run;
}

// ---------------------------------------------------------------------------
// k_fill: bucket edge ids by dst via cursor atomics.
// ---------------------------------------------------------------------------
__global__ void k_fill(const int* __restrict__ eidx,
                       int* __restrict__ cur,
                       int* __restrict__ elist)
{
    int e = blockIdx.x * 256 + threadIdx.x;
    int d = eidx[NEDGES + e];
    int pos = atomicAdd(&cur[d], 1);
    elist[pos] = e;
}

// ---------------------------------------------------------------------------
// Main fused kernel (round-7 body, verified 70us; single delta: A-register
// pipeline deepened 2->4 tiles, launch_bounds kept at (256,3) so the ~168
// VGPR budget absorbs the +16 regs without spilling).
// Wave roles (rotated per block):
//   role0: tiles [0,48)    W1    -> msg0   role1: [48,96)  W1+W2 -> msg0
//   role2: tiles [96,128)  W3    -> msg1   role3: [128,160) W4+W5 -> msg1
// TAIL=1: coalesced store of the 64x80 message tile to msgbuf (no atomics).
// ---------------------------------------------------------------------------
template<int TAIL>
__global__ __launch_bounds__(256, 3) void k_main(
    const int*   __restrict__ eidx,
    const float* __restrict__ node_feat,
    const float* __restrict__ edge_feat,
    const float* __restrict__ edge_embed,
    const u16*   __restrict__ ws,
    float*       __restrict__ msgbuf,
    float*       __restrict__ out)
{
    __shared__ __align__(16) char smem[40192];
    u16*   h1S   = (u16*)(smem);            // [64][72]  9216 B
    u16*   c12S  = (u16*)(smem + 9216);     // [48][64]  6144 B
    u16*   coefB = (u16*)(smem + 15360);    // [192][64] 24576 B
    int*   dstS  = (int*)(smem + 39936);    // 256 B
    u16*   h0S   = (u16*)(smem + 15360);    // alias: [64][72] during fc phase
    float* msgS  = (float*)(smem + 9216);   // alias: [64][81] f32 at reduce

    const int t    = threadIdx.x;
    const int lane = t & 63;
    const int l15  = lane & 15;
    const int lq   = lane >> 4;
    const int wid  = t >> 6;
    const int role = (wid + blockIdx.x) & 3;
    const int eg0  = blockIdx.x * EPB;

    const u16* WT2 = ws + WT2_OFF;
    const u16* WT0 = ws + WT0_OFF;
    const u16* WT1 = ws + WT1_OFF;

    // ---------------- fc0: h0 = silu(emb @ W0/8), 16 edges per wave --------
    {
        const float* erow = edge_embed + (size_t)(eg0 + wid * 16 + l15) * 64 + 8 * lq;
        bf16x8 eB0 = cvt_bf8(erow);
        bf16x8 eB1 = cvt_bf8(erow + 32);
        #pragma unroll
        for (int ntl = 0; ntl < 4; ++ntl) {
            const u16* a = WT0 + (ntl * 16 + l15) * 64 + 8 * lq;
            bf16x8 A0 = ld_bf8(a);
            bf16x8 A1 = ld_bf8(a + 32);
            f32x4 z = {0.f, 0.f, 0.f, 0.f};
            z = MFMA16(A0, eB0, z);
            f32x4 dd = MFMA16(A1, eB1, z);
            ushort4 pk;
            pk.x = f2bf(silu_n(dd[0]));
            pk.y = f2bf(silu_n(dd[1]));
            pk.z = f2bf(silu_n(dd[2]));
            pk.w = f2bf(silu_n(dd[3]));
            *(ushort4*)&h0S[(wid * 16 + l15) * HSTR + ntl * 16 + lq * 4] = pk;
        }
    }
    // ---------------- fc1: h1 = silu(h0 @ W1/8) (own wave's rows) ----------
    {
        const u16* hrow = h0S + (wid * 16 + l15) * HSTR + 8 * lq;
        bf16x8 hB0 = ld_bf8(hrow);
        bf16x8 hB1 = ld_bf8(hrow + 32);
        #pragma unroll
        for (int ntl = 0; ntl < 4; ++ntl) {
            const u16* a = WT1 + (ntl * 16 + l15) * 64 + 8 * lq;
            bf16x8 A0 = ld_bf8(a);
            bf16x8 A1 = ld_bf8(a + 32);
            f32x4 z = {0.f, 0.f, 0.f, 0.f};
            z = MFMA16(A0, hB0, z);
            f32x4 dd = MFMA16(A1, hB1, z);
            ushort4 pk;
            pk.x = f2bf(silu_n(dd[0]));
            pk.y = f2bf(silu_n(dd[1]));
            pk.z = f2bf(silu_n(dd[2]));
            pk.w = f2bf(silu_n(dd[3]));
            *(ushort4*)&h1S[(wid * 16 + l15) * HSTR + ntl * 16 + lq * 4] = pk;
        }
    }
    __syncthreads();   // h0S dead; coefB alias region reused below

    // ---------------- left-factor coef tables, 4 threads per edge ----------
    {
        const int e   = t & 63;
        const int q   = t >> 6;
        const int eg  = eg0 + e;
        const int src = eidx[eg];
        const float* nf = node_feat + (size_t)src * 80;
        const float* ef = edge_feat + (size_t)eg * 4;
        if (q == 0) {
            dstS[e] = eidx[NEDGES + eg];
            const float y0 = ef[0];
            #pragma unroll
            for (int u = 0; u < 32; ++u) c12S[u * 64 + e] = f2bf(nf[u] * y0);
        } else if (q == 1) {
            const float ya = ef[1], yb = ef[2], yc = ef[3];
            #pragma unroll
            for (int u = 0; u < 16; ++u) {
                float d = nf[32 + u * 3] * ya + nf[32 + u * 3 + 1] * yb
                        + nf[32 + u * 3 + 2] * yc;
                c12S[(32 + u) * 64 + e] = f2bf(d);
            }
        } else if (q == 2) {
            const float ya = ef[1], yb = ef[2], yc = ef[3];
            #pragma unroll
            for (int u = 0; u < 32; ++u) {
                const float x = nf[u];
                coefB[(u * 3 + 0) * 64 + e] = f2bf(x * ya);
                coefB[(u * 3 + 1) * 64 + e] = f2bf(x * yb);
                coefB[(u * 3 + 2) * 64 + e] = f2bf(x * yc);
            }
        } else {
            const float y0 = ef[0], ya = ef[1], yb = ef[2], yc = ef[3];
            #pragma unroll
            for (int u = 0; u < 16; ++u) {
                const float xa = nf[32 + u * 3], xb = nf[32 + u * 3 + 1], xc = nf[32 + u * 3 + 2];
                coefB[(96 + u * 3 + 0) * 64 + e] = f2bf(xa * y0);
                coefB[(96 + u * 3 + 1) * 64 + e] = f2bf(xb * y0);
                coefB[(96 + u * 3 + 2) * 64 + e] = f2bf(xc * y0);
                coefB[(144 + u * 3 + 0) * 64 + e] = f2bf(xb * yc - xc * yb);
                coefB[(144 + u * 3 + 1) * 64 + e] = f2bf(xc * ya - xa * yc);
                coefB[(144 + u * 3 + 2) * 64 + e] = f2bf(xa * yb - xb * ya);
            }
        }
    }
    __syncthreads();

    // ---------------- B fragments (all 64 edges) ---------------------------
    bf16x8 hb[4][2];
    #pragma unroll
    for (int eg = 0; eg < 4; ++eg) {
        const u16* r = h1S + (eg * 16 + l15) * HSTR + 8 * lq;
        hb[eg][0] = ld_bf8(r);
        hb[eg][1] = ld_bf8(r + 32);
    }

    float acc[48];
    #pragma unroll
    for (int i = 0; i < 48; ++i) acc[i] = 0.f;

    int t0, ntile;
    if (role < 2) { t0 = role * 48;            ntile = 48; }
    else          { t0 = 96 + (role - 2) * 32; ntile = 32; }

    const u16* Aw = WT2 + l15 * 64 + 8 * lq;   // + 1024 elems per tile

#define COMPUTE(A0_, A1_, D_)                                          \
    {                                                                  \
        _Pragma("unroll")                                              \
        for (int eg = 0; eg < 4; ++eg) {                               \
            f32x4 z = {0.f, 0.f, 0.f, 0.f};                            \
            z = MFMA16(A0_, hb[eg][0], z);                             \
            D_[eg] = MFMA16(A1_, hb[eg][1], z);                        \
        }                                                              \
    }

#define EPILOGUE(D_, TT_, HS_)                                              \
    {                                                                       \
        if (role < 2) {                                                     \
            const u16* cr = c12S + ((TT_) >> 1) * 64;                       \
            _Pragma("unroll")                                               \
            for (int eg = 0; eg < 4; ++eg) {                                \
                const float c = bf2f(cr[eg * 16 + l15]);                    \
                _Pragma("unroll")                                           \
                for (int r = 0; r < 4; ++r)                                 \
                    acc[eg * 8 + (HS_) * 4 + r] += c * D_[eg][r];           \
            }                                                               \
        } else {                                                            \
            const u16* cr = coefB + ((TT_) - 96) * 192;                     \
            _Pragma("unroll")                                               \
            for (int eg = 0; eg < 4; ++eg) {                                \
                const int e16 = eg * 16 + l15;                              \
                const float c0 = bf2f(cr[e16]);                             \
                const float c1 = bf2f(cr[64 + e16]);                        \
                const float c2 = bf2f(cr[128 + e16]);                       \
                _Pragma("unroll")                                           \
                for (int r = 0; r < 4; ++r) {                               \
                    const float dv = D_[eg][r];                             \
                    acc[eg * 12 + r * 3 + 0] += c0 * dv;                    \
                    acc[eg * 12 + r * 3 + 1] += c1 * dv;                    \
                    acc[eg * 12 + r * 3 + 2] += c2 * dv;                    \
                }                                                           \
            }                                                               \
        }                                                                   \
    }

    // ---------------- main fc2 loop: 4-tile P/Q ping-pong pipeline ---------
    bf16x8 Pa0, Pa1, Pb0, Pb1, Qa0, Qa1, Qb0, Qb1;
    {
        const u16* p0 = Aw + (size_t)(t0 + 0) * 1024;
        Pa0 = ld_bf8(p0); Pa1 = ld_bf8(p0 + 32);
        const u16* p1 = Aw + (size_t)(t0 + 1) * 1024;
        Pb0 = ld_bf8(p1); Pb1 = ld_bf8(p1 + 32);
        const u16* p2 = Aw + (size_t)(t0 + 2) * 1024;
        Qa0 = ld_bf8(p2); Qa1 = ld_bf8(p2 + 32);
        const u16* p3 = Aw + (size_t)(t0 + 3) * 1024;
        Qb0 = ld_bf8(p3); Qb1 = ld_bf8(p3 + 32);
    }
    const int nq = ntile >> 2;
    #pragma unroll 1
    for (int p = 0; p < nq; ++p) {
        const int tt = t0 + 4 * p;
        const bool more = (p + 1 < nq);
        f32x4 d[4];
        COMPUTE(Pa0, Pa1, d);
        EPILOGUE(d, tt, 0);
        if (more) { const u16* q_ = Aw + (size_t)(tt + 4) * 1024;
                    Pa0 = ld_bf8(q_); Pa1 = ld_bf8(q_ + 32); }
        COMPUTE(Pb0, Pb1, d);
        EPILOGUE(d, tt + 1, 1);
        if (more) { const u16* q_ = Aw + (size_t)(tt + 5) * 1024;
                    Pb0 = ld_bf8(q_); Pb1 = ld_bf8(q_ + 32); }
        COMPUTE(Qa0, Qa1, d);
        EPILOGUE(d, tt + 2, 0);
        if (more) { const u16* q_ = Aw + (size_t)(tt + 6) * 1024;
                    Qa0 = ld_bf8(q_); Qa1 = ld_bf8(q_ + 32); }
        COMPUTE(Qb0, Qb1, d);
        EPILOGUE(d, tt + 3, 1);
        if (more) { const u16* q_ = Aw + (size_t)(tt + 7) * 1024;
                    Qb0 = ld_bf8(q_); Qb1 = ld_bf8(q_ + 32); }
    }
#undef COMPUTE
#undef EPILOGUE

    // ---------------- cross-wave reduce (owner-ordered, no atomics) --------
    __syncthreads();   // all waves done reading c12S/coefB; msgS aliases them
    if (role == 0) {
        #pragma unroll
        for (int eg = 0; eg < 4; ++eg) {
            float* mb = msgS + (eg * 16 + l15) * 81;
            #pragma unroll
            for (int hs = 0; hs < 2; ++hs)
                #pragma unroll
                for (int r = 0; r < 4; ++r)
                    mb[hs * 16 + lq * 4 + r] = acc[eg * 8 + hs * 4 + r];
        }
    } else if (role == 2) {
        #pragma unroll
        for (int eg = 0; eg < 4; ++eg) {
            float* mb = msgS + (eg * 16 + l15) * 81 + 32;
            #pragma unroll
            for (int r = 0; r < 4; ++r)
                #pragma unroll
                for (int k = 0; k < 3; ++k)
                    mb[(lq * 4 + r) * 3 + k] = acc[eg * 12 + r * 3 + k];
        }
    }
    __syncthreads();
    if (role == 1) {
        #pragma unroll
        for (int eg = 0; eg < 4; ++eg) {
            float* mb = msgS + (eg * 16 + l15) * 81;
            #pragma unroll
            for (int hs = 0; hs < 2; ++hs)
                #pragma unroll
                for (int r = 0; r < 4; ++r)
                    mb[hs * 16 + lq * 4 + r] += acc[eg * 8 + hs * 4 + r];
        }
    } else if (role == 3) {
        #pragma unroll
        for (int eg = 0; eg < 4; ++eg) {
            float* mb = msgS + (eg * 16 + l15) * 81 + 32;
            #pragma unroll
            for (int r = 0; r < 4; ++r)
                #pragma unroll
                for (int k = 0; k < 3; ++k)
                    mb[(lq * 4 + r) * 3 + k] += acc[eg * 12 + r * 3 + k];
        }
    }
    __syncthreads();

    // ---------------- tail --------------------------------------------------
    if (TAIL == 1) {
        // coalesced store of the 64x80 tile to msgbuf (no atomics)
        float* mrow = msgbuf + (size_t)eg0 * 80;
        for (int idx = t; idx < EPB * 80; idx += 256) {
            const int e = idx / 80;
            const int s = idx - e * 80;
            mrow[idx] = msgS[e * 81 + s];
        }
    } else {
        // legacy atomic scatter (fallback when workspace is too small)
        for (int idx = t; idx < 64 * 81; idx += 256) {
            const int e = idx / 81;
            const int s = idx - e * 81;
            if (s < 80)
                atomicAdd(out + (size_t)dstS[e] * 80 + s, msgS[idx]);
        }
    }
}

// ---------------------------------------------------------------------------
// k_gather: one wave per node; sum its incident edges' msg rows, add to out.
// ---------------------------------------------------------------------------
__global__ __launch_bounds__(256) void k_gather(const int* __restrict__ ofs,
                                                const int* __restrict__ elist,
                                                const float* __restrict__ msg,
                                                float* __restrict__ out)
{
    const int lane = threadIdx.x & 63;
    const int n = blockIdx.x * 4 + (threadIdx.x >> 6);
    const int jb = ofs[n], je = ofs[n + 1];
    float v0 = 0.f, v1 = 0.f;
    int j = jb;
    for (; j + 2 <= je; j += 2) {
        const int e0 = elist[j], e1 = elist[j + 1];
        const float* m0 = msg + (size_t)e0 * 80;
        const float* m1 = msg + (size_t)e1 * 80;
        v0 += m0[lane] + m1[lane];
        if (lane < 16) v1 += m0[64 + lane] + m1[64 + lane];
    }
    if (j < je) {
        const float* m0 = msg + (size_t)elist[j] * 80;
        v0 += m0[lane];
        if (lane < 16) v1 += m0[64 + lane];
    }
    float* op = out + (size_t)n * 80;
    op[lane] += v0;
    if (lane < 16) op[64 + lane] += v1;
}

extern "C" void kernel_launch(void* const* d_in, const int* in_sizes, int n_in,
                              void* d_out, int out_size, void* d_ws, size_t ws_size,
                              hipStream_t stream) {
    const int*   eidx       = (const int*)d_in[0];
    const float* node_feat  = (const float*)d_in[1];
    const float* edge_feat  = (const float*)d_in[2];
    const float* edge_embed = (const float*)d_in[3];
    const float* Wfc0       = (const float*)d_in[5];
    const float* Wfc1       = (const float*)d_in[6];
    const float* Wfc2       = (const float*)d_in[7];
    const float* Wsc0       = (const float*)d_in[8];
    const float* Wsc1       = (const float*)d_in[9];
    float* out = (float*)d_out;
    char*  wsb = (char*)d_ws;
    u16*   ws  = (u16*)d_ws;

    if (ws_size < (size_t)WS_ELEMS * sizeof(u16)) return;  // need >= 344 KB

    const bool big = ws_size >= (size_t)WS_NEED;
    int*   cnt    = (int*)(wsb + OFF_CNT);
    int*   ofs    = (int*)(wsb + OFF_OFS);
    int*   cur    = (int*)(wsb + OFF_CUR);
    int*   elist  = (int*)(wsb + OFF_ELIST);
    float* msgbuf = (float*)(wsb + OFF_MSG);

    if (big) {
        hipLaunchKernelGGL(k_zero, dim3(32), dim3(256), 0, stream, cnt);
        hipLaunchKernelGGL(k_prep, dim3(3488), dim3(256), 0, stream,
                           Wfc0, Wfc1, Wfc2, node_feat, Wsc0, Wsc1, eidx, ws, cnt, out);
        hipLaunchKernelGGL(k_scan, dim3(1), dim3(1024), 0, stream, cnt, ofs, cur);
        hipLaunchKernelGGL(k_fill, dim3(NEDGES / 256), dim3(256), 0, stream,
                           eidx, cur, elist);
        hipLaunchKernelGGL((k_main<1>), dim3(NEDGES / EPB), dim3(256), 0, stream,
                           eidx, node_feat, edge_feat, edge_embed, ws, msgbuf, out);
        hipLaunchKernelGGL(k_gather, dim3(NNODES / 4), dim3(256), 0, stream,
                           ofs, elist, msgbuf, out);
    } else {
        hipLaunchKernelGGL(k_prep, dim3(3232), dim3(256), 0, stream,
                           Wfc0, Wfc1, Wfc2, node_feat, Wsc0, Wsc1, eidx, ws, cnt, out);
        hipLaunchKernelGGL((k_main<0>), dim3(NEDGES / EPB), dim3(256), 0, stream,
                           eidx, node_feat, edge_feat, edge_embed, ws, msgbuf, out);
    }
}

// Round 11
// 101.026 us; speedup vs baseline: 2.3164x; 1.0086x over previous
//
#include <hip/hip_runtime.h>

typedef unsigned short u16;
typedef __bf16 bf16x8 __attribute__((ext_vector_type(8)));
typedef float  f32x4  __attribute__((ext_vector_type(4)));

#define NEDGES 65536
#define NNODES 8192
#define EPB 64

#define PW0f       0.14433756729740643f   // (1/48)^0.5
#define PW1f       0.21650635094610965f   // (3/64)^0.5
#define INV_SQRT3f 0.5773502691896258f
#define INV_SQRT6f 0.4082482904638631f
#define SILU_NORMf 1.6790425f

// workspace layout (bytes)
#define WT2_OFF 0          // u16[2560][64]  Wfc2^T, 0.125*region scale folded
#define WT0_OFF 163840     // u16 elem offset: [64][64] Wfc0^T * 0.125
#define WT1_OFF 167936     // u16 elem offset: [64][64] Wfc1^T * 0.125
#define WS_ELEMS 172032    // u16 elements of weight tables

#define OFF_CNT   344064   // int[8192]   per-node edge count
#define OFF_OFS   376832   // int[8193]   CSR offsets
#define OFF_CUR   409856   // int[8192]   fill cursors
#define OFF_ELIST 442624   // int[65536]  edge ids grouped by dst
#define OFF_MSG   704768   // float[65536][80] per-edge messages
#define WS_NEED   21676288

#define HSTR 72            // padded bf16 row stride for h0/h1 LDS tiles

__device__ __forceinline__ float silu_n(float z) {
    return SILU_NORMf * z / (1.0f + __expf(-z));
}
__device__ __forceinline__ u16 f2bf(float f) {
    return __builtin_bit_cast(u16, (__bf16)f);
}
__device__ __forceinline__ float bf2f(u16 u) {
    unsigned v = ((unsigned)u) << 16;
    return __builtin_bit_cast(float, v);
}
__device__ __forceinline__ bf16x8 ld_bf8(const u16* p) {
    return *reinterpret_cast<const bf16x8*>(p);
}
__device__ __forceinline__ bf16x8 cvt_bf8(const float* p) {
    float4 a = *reinterpret_cast<const float4*>(p);
    float4 b = *reinterpret_cast<const float4*>(p + 4);
    bf16x8 r;
    r[0]=(__bf16)a.x; r[1]=(__bf16)a.y; r[2]=(__bf16)a.z; r[3]=(__bf16)a.w;
    r[4]=(__bf16)b.x; r[5]=(__bf16)b.y; r[6]=(__bf16)b.z; r[7]=(__bf16)b.w;
    return r;
}
#define MFMA16(A,B,C) __builtin_amdgcn_mfma_f32_16x16x32_bf16(A,B,C,0,0,0)

// ---------------------------------------------------------------------------
// k_zero: clear the per-node histogram counters.
// ---------------------------------------------------------------------------
__global__ void k_zero(int* __restrict__ cnt) {
    int i = blockIdx.x * 256 + threadIdx.x;
    if (i < NNODES) cnt[i] = 0;
}

// ---------------------------------------------------------------------------
// Prep kernel (fused): blocks [0,672) transpose+scale+bf16 the MLP weights
// into d_ws; blocks [672,3232) compute the self-connection into d_out
// (re-initializes d_out every call); blocks [3232,3488) histogram dst.
// ---------------------------------------------------------------------------
__global__ void k_prep(const float* __restrict__ Wfc0,
                       const float* __restrict__ Wfc1,
                       const float* __restrict__ Wfc2,
                       const float* __restrict__ node_feat,
                       const float* __restrict__ Wsc0,
                       const float* __restrict__ Wsc1,
                       const int*   __restrict__ eidx,
                       u16* __restrict__ ws,
                       int* __restrict__ cnt,
                       float* __restrict__ out)
{
    const int bid = blockIdx.x;
    if (bid < 672) {
        int gid = bid * 256 + threadIdx.x;
        if (gid < 163840) {                 // gid = k*2560 + j (read-coalesced)
            int k = gid / 2560;
            int j = gid - k * 2560;
            float s;
            if (j < 1024)      s = PW0f;
            else if (j < 1536) s = PW0f * INV_SQRT3f;
            else if (j < 2304) s = PW1f * INV_SQRT3f;
            else               s = PW1f * INV_SQRT6f;
            ws[WT2_OFF + j * 64 + k] = f2bf(Wfc2[gid] * (0.125f * s));
        } else if (gid < WT1_OFF) {
            int i = gid - WT0_OFF;
            int k = i >> 6, n = i & 63;
            ws[WT0_OFF + n * 64 + k] = f2bf(Wfc0[i] * 0.125f);
        } else if (gid < WS_ELEMS) {
            int i = gid - WT1_OFF;
            int k = i >> 6, n = i & 63;
            ws[WT1_OFF + n * 64 + k] = f2bf(Wfc1[i] * 0.125f);
        }
    } else if (bid < 3232) {
        int gid = (bid - 672) * 256 + threadIdx.x;
        if (gid >= NNODES * 80) return;
        int n = gid / 80;
        int s = gid - n * 80;
        const float* nf = node_feat + (size_t)n * 80;
        float r;
        if (s < 32) {
            float a = 0.f;
            #pragma unroll
            for (int u = 0; u < 32; ++u) a += nf[u] * Wsc0[u * 32 + s];
            r = a * 0.17677669529663687f;   // 1/sqrt(32)
        } else {
            int v = (s - 32) / 3;
            int k = (s - 32) - v * 3;
            float a = 0.f;
            #pragma unroll
            for (int u = 0; u < 16; ++u) a += nf[32 + u * 3 + k] * Wsc1[u * 16 + v];
            r = a * 0.25f;                   // 1/sqrt(16)
        }
        out[gid] = r;
    } else {
        int e = (bid - 3232) * 256 + threadIdx.x;
        if (e < NEDGES) atomicAdd(&cnt[eidx[NEDGES + e]], 1);
    }
}

// ---------------------------------------------------------------------------
// k_scan: exclusive prefix sum over cnt[8192] -> ofs[8193], cur = ofs copy.
// ---------------------------------------------------------------------------
__global__ __launch_bounds__(1024) void k_scan(const int* __restrict__ cnt,
                                               int* __restrict__ ofs,
                                               int* __restrict__ cur)
{
    __shared__ int ps[1024];
    const int t = threadIdx.x;
    const int base = t * 8;
    int v[8]; int s = 0;
    #pragma unroll
    for (int i = 0; i < 8; ++i) { v[i] = cnt[base + i]; s += v[i]; }
    ps[t] = s;
    __syncthreads();
    int acc = s;
    for (int off = 1; off < 1024; off <<= 1) {
        int x = (t >= off) ? ps[t - off] : 0;
        __syncthreads();
        acc += x;
        ps[t] = acc;
        __syncthreads();
    }
    int run = acc - s;                       // exclusive base for this thread
    #pragma unroll
    for (int i = 0; i < 8; ++i) { ofs[base + i] = run; cur[base + i] = run; run += v[i]; }
    if (t == 1023) ofs[NNODES] = run;
}

// ---------------------------------------------------------------------------
// k_fill: bucket edge ids by dst via cursor atomics.
// ---------------------------------------------------------------------------
__global__ void k_fill(const int* __restrict__ eidx,
                       int* __restrict__ cur,
                       int* __restrict__ elist)
{
    int e = blockIdx.x * 256 + threadIdx.x;
    int d = eidx[NEDGES + e];
    int pos = atomicAdd(&cur[d], 1);
    elist[pos] = e;
}

// ---------------------------------------------------------------------------
// Main fused kernel: r10 loop + r6-verified packed tables, LDS 36864 so four
// blocks/CU fit; launch_bounds (256,2) gives the compiler ~128 VGPR so the
// 4-deep pipeline survives without spill (runtime residency is resource-
// determined: VGPR<=128 -> 4 waves/SIMD, LDS*4=147KB -> 4 blocks).
// Wave roles (rotated per block):
//   role0: tiles [0,44)    W1                        -> msg0 (32 acc)
//   role1: tiles [44,88)   W1+W2                     -> msg0 (32)
//   role2: tiles [88,128)  W2 + W3(factored s-vec)   -> msg0 (32) + s (16)
//   role3: tiles [128,160) W4+W5 (ushort4-packed)    -> msg1 (48)
// TAIL=1: coalesced store of the 64x80 message tile to msgbuf (no atomics).
// ---------------------------------------------------------------------------
template<int TAIL>
__global__ __launch_bounds__(256, 2) void k_main(
    const int*   __restrict__ eidx,
    const float* __restrict__ node_feat,
    const float* __restrict__ edge_feat,
    const float* __restrict__ edge_embed,
    const u16*   __restrict__ ws,
    float*       __restrict__ msgbuf,
    float*       __restrict__ out)
{
    __shared__ __align__(16) char smem[36864];
    u16*   h1S  = (u16*)(smem);              // [64][72] 9216 B (persistent)
    u16*   c12S = (u16*)(smem + 9216);       // [48][64] 6144 B (u<32: x0*y0, else dot)
    u16*   x0S  = (u16*)(smem + 15360);      // [32][64] 4096 B (raw x0, bf16)
    u16*   w4S  = (u16*)(smem + 19456);      // [16][64][4] 8192 B (x1*y0, k-packed)
    u16*   w5S  = (u16*)(smem + 27648);      // [16][64][4] 8192 B (cross, k-packed)
    float* y1S  = (float*)(smem + 35840);    // [3][64] 768 B
    int*   dstS = (int*)(smem + 36608);      // [64] 256 B
    u16*   h0S  = (u16*)(smem + 9216);       // alias: [64][72] during fc phase only
    float* msgS = (float*)(smem + 9216);     // alias: [64][81] f32 = 20736 B (reduce;
                                             // covers c12S/x0S/w4S/w5S-head, dead then)

    const int t    = threadIdx.x;
    const int lane = t & 63;
    const int l15  = lane & 15;
    const int lq   = lane >> 4;
    const int wid  = t >> 6;
    const int role = (wid + blockIdx.x) & 3;
    const int eg0  = blockIdx.x * EPB;

    const u16* WT2 = ws + WT2_OFF;
    const u16* WT0 = ws + WT0_OFF;
    const u16* WT1 = ws + WT1_OFF;

    // ---------------- fc0: h0 = silu(emb @ W0/8), 16 edges per wave --------
    {
        const float* erow = edge_embed + (size_t)(eg0 + wid * 16 + l15) * 64 + 8 * lq;
        bf16x8 eB0 = cvt_bf8(erow);
        bf16x8 eB1 = cvt_bf8(erow + 32);
        #pragma unroll
        for (int ntl = 0; ntl < 4; ++ntl) {
            const u16* a = WT0 + (ntl * 16 + l15) * 64 + 8 * lq;
            bf16x8 A0 = ld_bf8(a);
            bf16x8 A1 = ld_bf8(a + 32);
            f32x4 z = {0.f, 0.f, 0.f, 0.f};
            z = MFMA16(A0, eB0, z);
            f32x4 dd = MFMA16(A1, eB1, z);
            ushort4 pk;
            pk.x = f2bf(silu_n(dd[0]));
            pk.y = f2bf(silu_n(dd[1]));
            pk.z = f2bf(silu_n(dd[2]));
            pk.w = f2bf(silu_n(dd[3]));
            *(ushort4*)&h0S[(wid * 16 + l15) * HSTR + ntl * 16 + lq * 4] = pk;
        }
    }
    // ---------------- fc1: h1 = silu(h0 @ W1/8) (own wave's rows) ----------
    {
        const u16* hrow = h0S + (wid * 16 + l15) * HSTR + 8 * lq;
        bf16x8 hB0 = ld_bf8(hrow);
        bf16x8 hB1 = ld_bf8(hrow + 32);
        #pragma unroll
        for (int ntl = 0; ntl < 4; ++ntl) {
            const u16* a = WT1 + (ntl * 16 + l15) * 64 + 8 * lq;
            bf16x8 A0 = ld_bf8(a);
            bf16x8 A1 = ld_bf8(a + 32);
            f32x4 z = {0.f, 0.f, 0.f, 0.f};
            z = MFMA16(A0, hB0, z);
            f32x4 dd = MFMA16(A1, hB1, z);
            ushort4 pk;
            pk.x = f2bf(silu_n(dd[0]));
            pk.y = f2bf(silu_n(dd[1]));
            pk.z = f2bf(silu_n(dd[2]));
            pk.w = f2bf(silu_n(dd[3]));
            *(ushort4*)&h1S[(wid * 16 + l15) * HSTR + ntl * 16 + lq * 4] = pk;
        }
    }
    __syncthreads();   // h0S dead; its alias region (c12S/x0S) reused below

    // ---------------- left-factor tables, 4 threads per edge ---------------
    {
        const int e   = t & 63;
        const int q   = t >> 6;
        const int eg  = eg0 + e;
        const int src = eidx[eg];
        const float* nf = node_feat + (size_t)src * 80;
        const float* ef = edge_feat + (size_t)eg * 4;
        if (q == 0) {
            dstS[e] = eidx[NEDGES + eg];
            const float y0 = ef[0];
            y1S[e] = ef[1]; y1S[64 + e] = ef[2]; y1S[128 + e] = ef[3];
            #pragma unroll
            for (int u = 0; u < 32; ++u) c12S[u * 64 + e] = f2bf(nf[u] * y0);
        } else if (q == 1) {
            const float ya = ef[1], yb = ef[2], yc = ef[3];
            #pragma unroll
            for (int u = 0; u < 16; ++u) {
                float d = nf[32 + u * 3] * ya + nf[32 + u * 3 + 1] * yb
                        + nf[32 + u * 3 + 2] * yc;
                c12S[(32 + u) * 64 + e] = f2bf(d);
            }
            #pragma unroll
            for (int u = 0; u < 32; ++u) x0S[u * 64 + e] = f2bf(nf[u]);
        } else if (q == 2) {
            const float y0 = ef[0];
            #pragma unroll
            for (int u = 0; u < 16; ++u) {
                ushort4 pk;
                pk.x = f2bf(nf[32 + u * 3 + 0] * y0);
                pk.y = f2bf(nf[32 + u * 3 + 1] * y0);
                pk.z = f2bf(nf[32 + u * 3 + 2] * y0);
                pk.w = 0;
                *(ushort4*)&w4S[(u * 64 + e) * 4] = pk;
            }
        } else {
            const float ya = ef[1], yb = ef[2], yc = ef[3];
            #pragma unroll
            for (int u = 0; u < 16; ++u) {
                const float xa = nf[32 + u * 3], xb = nf[32 + u * 3 + 1], xc = nf[32 + u * 3 + 2];
                ushort4 pk;
                pk.x = f2bf(xb * yc - xc * yb);
                pk.y = f2bf(xc * ya - xa * yc);
                pk.z = f2bf(xa * yb - xb * ya);
                pk.w = 0;
                *(ushort4*)&w5S[(u * 64 + e) * 4] = pk;
            }
        }
    }
    __syncthreads();

    // ---------------- B fragments (all 64 edges) ---------------------------
    bf16x8 hb[4][2];
    #pragma unroll
    for (int eg = 0; eg < 4; ++eg) {
        const u16* r = h1S + (eg * 16 + l15) * HSTR + 8 * lq;
        hb[eg][0] = ld_bf8(r);
        hb[eg][1] = ld_bf8(r + 32);
    }

    // acc: roles 0/1: [0..31] msg0. role2: [0..31] msg0 + [32..47] s-vec.
    //      role3: [0..47] msg1 (eg*12 + r*3 + k).
    float acc[48];
    #pragma unroll
    for (int i = 0; i < 48; ++i) acc[i] = 0.f;

    int t0, ntile;
    if      (role == 0) { t0 = 0;   ntile = 44; }
    else if (role == 1) { t0 = 44;  ntile = 44; }
    else if (role == 2) { t0 = 88;  ntile = 40; }
    else                { t0 = 128; ntile = 32; }

    const u16* Aw = WT2 + l15 * 64 + 8 * lq;   // + 1024 elems per tile

#define COMPUTE(A0_, A1_, D_)                                          \
    {                                                                  \
        _Pragma("unroll")                                              \
        for (int eg = 0; eg < 4; ++eg) {                               \
            f32x4 z = {0.f, 0.f, 0.f, 0.f};                            \
            z = MFMA16(A0_, hb[eg][0], z);                             \
            D_[eg] = MFMA16(A1_, hb[eg][1], z);                        \
        }                                                              \
    }

#define EPILOGUE(D_, TT_, HS_)                                               \
    {                                                                        \
        if ((TT_) < 96) {                   /* W1/W2 -> msg0 partial */      \
            const u16* cr = c12S + ((TT_) >> 1) * 64;                        \
            _Pragma("unroll")                                                \
            for (int eg = 0; eg < 4; ++eg) {                                 \
                const float c = bf2f(cr[eg * 16 + l15]);                     \
                _Pragma("unroll")                                            \
                for (int r = 0; r < 4; ++r)                                  \
                    acc[eg * 8 + (HS_) * 4 + r] += c * D_[eg][r];            \
            }                                                                \
        } else if ((TT_) < 128) {           /* W3 factored: s += x0[u]*d */  \
            const u16* cr = x0S + ((TT_) - 96) * 64;                         \
            _Pragma("unroll")                                                \
            for (int eg = 0; eg < 4; ++eg) {                                 \
                const float c = bf2f(cr[eg * 16 + l15]);                     \
                _Pragma("unroll")                                            \
                for (int r = 0; r < 4; ++r)                                  \
                    acc[32 + eg * 4 + r] += c * D_[eg][r];                   \
            }                                                                \
        } else {                            /* W4/W5 -> msg1 direct */       \
            const u16* cr = ((TT_) < 144 ? w4S + ((TT_) - 128) * 256         \
                                         : w5S + ((TT_) - 144) * 256);       \
            _Pragma("unroll")                                                \
            for (int eg = 0; eg < 4; ++eg) {                                 \
                const ushort4 cw = *(const ushort4*)&cr[(eg * 16 + l15) * 4];\
                const float c0 = bf2f(cw.x);                                 \
                const float c1 = bf2f(cw.y);                                 \
                const float c2 = bf2f(cw.z);                                 \
                _Pragma("unroll")                                            \
                for (int r = 0; r < 4; ++r) {                                \
                    const float dv = D_[eg][r];                              \
                    acc[eg * 12 + r * 3 + 0] += c0 * dv;                     \
                    acc[eg * 12 + r * 3 + 1] += c1 * dv;                     \
                    acc[eg * 12 + r * 3 + 2] += c2 * dv;                     \
                }                                                            \
            }                                                                \
        }                                                                    \
    }

    // ---------------- main fc2 loop: 4-tile P/Q ping-pong pipeline ---------
    bf16x8 Pa0, Pa1, Pb0, Pb1, Qa0, Qa1, Qb0, Qb1;
    {
        const u16* p0 = Aw + (size_t)(t0 + 0) * 1024;
        Pa0 = ld_bf8(p0); Pa1 = ld_bf8(p0 + 32);
        const u16* p1 = Aw + (size_t)(t0 + 1) * 1024;
        Pb0 = ld_bf8(p1); Pb1 = ld_bf8(p1 + 32);
        const u16* p2 = Aw + (size_t)(t0 + 2) * 1024;
        Qa0 = ld_bf8(p2); Qa1 = ld_bf8(p2 + 32);
        const u16* p3 = Aw + (size_t)(t0 + 3) * 1024;
        Qb0 = ld_bf8(p3); Qb1 = ld_bf8(p3 + 32);
    }
    const int nq = ntile >> 2;
    #pragma unroll 1
    for (int p = 0; p < nq; ++p) {
        const int tt = t0 + 4 * p;
        const bool more = (p + 1 < nq);
        f32x4 d[4];
        COMPUTE(Pa0, Pa1, d);
        EPILOGUE(d, tt, 0);
        if (more) { const u16* q_ = Aw + (size_t)(tt + 4) * 1024;
                    Pa0 = ld_bf8(q_); Pa1 = ld_bf8(q_ + 32); }
        COMPUTE(Pb0, Pb1, d);
        EPILOGUE(d, tt + 1, 1);
        if (more) { const u16* q_ = Aw + (size_t)(tt + 5) * 1024;
                    Pb0 = ld_bf8(q_); Pb1 = ld_bf8(q_ + 32); }
        COMPUTE(Qa0, Qa1, d);
        EPILOGUE(d, tt + 2, 0);
        if (more) { const u16* q_ = Aw + (size_t)(tt + 6) * 1024;
                    Qa0 = ld_bf8(q_); Qa1 = ld_bf8(q_ + 32); }
        COMPUTE(Qb0, Qb1, d);
        EPILOGUE(d, tt + 3, 1);
        if (more) { const u16* q_ = Aw + (size_t)(tt + 7) * 1024;
                    Qb0 = ld_bf8(q_); Qb1 = ld_bf8(q_ + 32); }
    }
#undef COMPUTE
#undef EPILOGUE

    // ---------------- cross-wave reduce (owner-ordered, NO atomics) --------
    __syncthreads();   // all waves done reading tables; msgS aliases them
    if (role == 0) {
        #pragma unroll
        for (int eg = 0; eg < 4; ++eg) {
            float* mb = msgS + (eg * 16 + l15) * 81;
            #pragma unroll
            for (int hs = 0; hs < 2; ++hs)
                #pragma unroll
                for (int r = 0; r < 4; ++r)
                    mb[hs * 16 + lq * 4 + r] = acc[eg * 8 + hs * 4 + r];
        }
    } else if (role == 3) {
        #pragma unroll
        for (int eg = 0; eg < 4; ++eg) {
            float* mb = msgS + (eg * 16 + l15) * 81 + 32;
            #pragma unroll
            for (int r = 0; r < 4; ++r)
                #pragma unroll
                for (int k = 0; k < 3; ++k)
                    mb[(lq * 4 + r) * 3 + k] = acc[eg * 12 + r * 3 + k];
        }
    }
    __syncthreads();
    if (role == 1) {
        #pragma unroll
        for (int eg = 0; eg < 4; ++eg) {
            float* mb = msgS + (eg * 16 + l15) * 81;
            #pragma unroll
            for (int hs = 0; hs < 2; ++hs)
                #pragma unroll
                for (int r = 0; r < 4; ++r)
                    mb[hs * 16 + lq * 4 + r] += acc[eg * 8 + hs * 4 + r];
        }
    } else if (role == 2) {
        // W3: msg1 += s (x) y1   (sole msg1 writer this phase)
        #pragma unroll
        for (int eg = 0; eg < 4; ++eg) {
            const int e = eg * 16 + l15;
            const float w1x = y1S[e], w1y = y1S[64 + e], w1z = y1S[128 + e];
            float* mb = msgS + e * 81 + 32;
            #pragma unroll
            for (int r = 0; r < 4; ++r) {
                const float s = acc[32 + eg * 4 + r];
                mb[(lq * 4 + r) * 3 + 0] += s * w1x;
                mb[(lq * 4 + r) * 3 + 1] += s * w1y;
                mb[(lq * 4 + r) * 3 + 2] += s * w1z;
            }
        }
    }
    __syncthreads();
    if (role == 2) {
        // role2's W2 partial into msg0 (sole msg0 writer this phase)
        #pragma unroll
        for (int eg = 0; eg < 4; ++eg) {
            float* mb = msgS + (eg * 16 + l15) * 81;
            #pragma unroll
            for (int hs = 0; hs < 2; ++hs)
                #pragma unroll
                for (int r = 0; r < 4; ++r)
                    mb[hs * 16 + lq * 4 + r] += acc[eg * 8 + hs * 4 + r];
        }
    }
    __syncthreads();

    // ---------------- tail --------------------------------------------------
    if (TAIL == 1) {
        // coalesced store of the 64x80 tile to msgbuf (no atomics)
        float* mrow = msgbuf + (size_t)eg0 * 80;
        for (int idx = t; idx < EPB * 80; idx += 256) {
            const int e = idx / 80;
            const int s = idx - e * 80;
            mrow[idx] = msgS[e * 81 + s];
        }
    } else {
        // legacy atomic scatter (fallback when workspace is too small)
        for (int idx = t; idx < 64 * 81; idx += 256) {
            const int e = idx / 81;
            const int s = idx - e * 81;
            if (s < 80)
                atomicAdd(out + (size_t)dstS[e] * 80 + s, msgS[idx]);
        }
    }
}

// ---------------------------------------------------------------------------
// k_gather: one wave per node; sum its incident edges' msg rows, add to out.
// ---------------------------------------------------------------------------
__global__ __launch_bounds__(256) void k_gather(const int* __restrict__ ofs,
                                                const int* __restrict__ elist,
                                                const float* __restrict__ msg,
                                                float* __restrict__ out)
{
    const int lane = threadIdx.x & 63;
    const int n = blockIdx.x * 4 + (threadIdx.x >> 6);
    const int jb = ofs[n], je = ofs[n + 1];
    float v0 = 0.f, v1 = 0.f;
    int j = jb;
    for (; j + 2 <= je; j += 2) {
        const int e0 = elist[j], e1 = elist[j + 1];
        const float* m0 = msg + (size_t)e0 * 80;
        const float* m1 = msg + (size_t)e1 * 80;
        v0 += m0[lane] + m1[lane];
        if (lane < 16) v1 += m0[64 + lane] + m1[64 + lane];
    }
    if (j < je) {
        const float* m0 = msg + (size_t)elist[j] * 80;
        v0 += m0[lane];
        if (lane < 16) v1 += m0[64 + lane];
    }
    float* op = out + (size_t)n * 80;
    op[lane] += v0;
    if (lane < 16) op[64 + lane] += v1;
}

extern "C" void kernel_launch(void* const* d_in, const int* in_sizes, int n_in,
                              void* d_out, int out_size, void* d_ws, size_t ws_size,
                              hipStream_t stream) {
    const int*   eidx       = (const int*)d_in[0];
    const float* node_feat  = (const float*)d_in[1];
    const float* edge_feat  = (const float*)d_in[2];
    const float* edge_embed = (const float*)d_in[3];
    const float* Wfc0       = (const float*)d_in[5];
    const float* Wfc1       = (const float*)d_in[6];
    const float* Wfc2       = (const float*)d_in[7];
    const float* Wsc0       = (const float*)d_in[8];
    const float* Wsc1       = (const float*)d_in[9];
    float* out = (float*)d_out;
    char*  wsb = (char*)d_ws;
    u16*   ws  = (u16*)d_ws;

    if (ws_size < (size_t)WS_ELEMS * sizeof(u16)) return;  // need >= 344 KB

    const bool big = ws_size >= (size_t)WS_NEED;
    int*   cnt    = (int*)(wsb + OFF_CNT);
    int*   ofs    = (int*)(wsb + OFF_OFS);
    int*   cur    = (int*)(wsb + OFF_CUR);
    int*   elist  = (int*)(wsb + OFF_ELIST);
    float* msgbuf = (float*)(wsb + OFF_MSG);

    if (big) {
        hipLaunchKernelGGL(k_zero, dim3(32), dim3(256), 0, stream, cnt);
        hipLaunchKernelGGL(k_prep, dim3(3488), dim3(256), 0, stream,
                           Wfc0, Wfc1, Wfc2, node_feat, Wsc0, Wsc1, eidx, ws, cnt, out);
        hipLaunchKernelGGL(k_scan, dim3(1), dim3(1024), 0, stream, cnt, ofs, cur);
        hipLaunchKernelGGL(k_fill, dim3(NEDGES / 256), dim3(256), 0, stream,
                           eidx, cur, elist);
        hipLaunchKernelGGL((k_main<1>), dim3(NEDGES / EPB), dim3(256), 0, stream,
                           eidx, node_feat, edge_feat, edge_embed, ws, msgbuf, out);
        hipLaunchKernelGGL(k_gather, dim3(NNODES / 4), dim3(256), 0, stream,
                           ofs, elist, msgbuf, out);
    } else {
        hipLaunchKernelGGL(k_prep, dim3(3232), dim3(256), 0, stream,
                           Wfc0, Wfc1, Wfc2, node_feat, Wsc0, Wsc1, eidx, ws, cnt, out);
        hipLaunchKernelGGL((k_main<0>), dim3(NEDGES / EPB), dim3(256), 0, stream,
                           eidx, node_feat, edge_feat, edge_embed, ws, msgbuf, out);
    }
}